// Round 2
// baseline (1952.972 us; speedup 1.0000x reference)
//
#include <hip/hip_runtime.h>

// Problem constants
static constexpr int BB = 4;
static constexpr int SS = 4096;
static constexpr int DD = 1024;
static constexpr int HH = 8;
static constexpr int HD = 128;     // FFT length
static constexpr int CS = 64;      // scan chunk size (positions per block)
static constexpr int NCHUNK = SS / CS;   // 64
static constexpr int MROWS = BB * SS;    // 16384

// ---------------------------------------------------------------------------
// bf16 helpers (manual, RNE) — vals is stored bf16 to keep ws under ~237 MB
// ---------------------------------------------------------------------------
__device__ __forceinline__ float bf2f(unsigned short u) {
    unsigned int x = ((unsigned int)u) << 16;
    return __uint_as_float(x);
}
__device__ __forceinline__ unsigned short f2bf(float f) {
    unsigned int x = __float_as_uint(f);
    unsigned int r = x + 0x7FFFu + ((x >> 16) & 1u);
    return (unsigned short)(r >> 16);
}

// ---------------------------------------------------------------------------
// Complex helpers
// ---------------------------------------------------------------------------
struct cpx { float re, im; };

__device__ __forceinline__ cpx cadd(cpx a, cpx b) { return {a.re + b.re, a.im + b.im}; }
__device__ __forceinline__ cpx csub(cpx a, cpx b) { return {a.re - b.re, a.im - b.im}; }
__device__ __forceinline__ cpx cmul(cpx a, cpx b) {
    return { fmaf(a.re, b.re, -a.im * b.im), fmaf(a.re, b.im, a.im * b.re) };
}
// a * conj(b)
__device__ __forceinline__ cpx cmul_cj(cpx a, cpx b) {
    return { fmaf(a.re, b.re, a.im * b.im), fmaf(a.im, b.re, -a.re * b.im) };
}
__device__ __forceinline__ cpx shflx(cpx x, int m) {
    return { __shfl_xor(x.re, m), __shfl_xor(x.im, m) };
}

// Twiddles depend only on (lane, stage): compute once per thread.
// tw[0]: intra-lane stage d=64: W_128^lane
// tw[s], s=1..6: lane stages d=32,16,8,4,2,1: W_{2d}^{lane & (d-1)}
__device__ __forceinline__ void make_tw(int lane, cpx tw[7]) {
    const float NEG2PI = -6.28318530717958647692f;
    float a0 = NEG2PI * (float)lane * (1.0f / 128.0f);
    tw[0] = { __cosf(a0), __sinf(a0) };
    int d = 32;
#pragma unroll
    for (int s = 1; s <= 6; ++s) {
        int i = lane & (d - 1);
        float a = NEG2PI * (float)i / (float)(2 * d);
        tw[s] = { __cosf(a), __sinf(a) };
        d >>= 1;
    }
}

// Forward DIF FFT-128: natural order in (x0 = elem lane, x1 = elem lane+64),
// bit-reversed-permuted order out. Unnormalized.
__device__ __forceinline__ void fft128_fwd(cpx& x0, cpx& x1, const cpx tw[7], int lane) {
    // intra-lane stage d=64
    cpx a = x0, b = x1;
    x0 = cadd(a, b);
    x1 = cmul(csub(a, b), tw[0]);
    int d = 32;
#pragma unroll
    for (int s = 1; s <= 6; ++s) {
        const bool up = (lane & d) != 0;
        cpx o0 = shflx(x0, d);
        cpx o1 = shflx(x1, d);
        cpx s0 = cadd(x0, o0);                 // lower lane: a + b
        cpx s1 = cadd(x1, o1);
        cpx d0 = cmul(csub(o0, x0), tw[s]);    // upper lane: (a - b) * W
        cpx d1 = cmul(csub(o1, x1), tw[s]);
        x0 = up ? d0 : s0;
        x1 = up ? d1 : s1;
        d >>= 1;
    }
}

// Inverse DIT FFT-128: consumes fft128_fwd's permuted order, outputs natural
// order, includes the 1/128 normalization.
__device__ __forceinline__ void fft128_inv(cpx& x0, cpx& x1, const cpx tw[7], int lane) {
    int d = 1;
#pragma unroll
    for (int s = 6; s >= 1; --s) {
        const bool up = (lane & d) != 0;
        cpx o0 = shflx(x0, d);
        cpx o1 = shflx(x1, d);
        cpx b0 = up ? x0 : o0;   // b' value
        cpx a0 = up ? o0 : x0;   // a' value
        cpx b1 = up ? x1 : o1;
        cpx a1 = up ? o1 : x1;
        cpx t0 = cmul_cj(b0, tw[s]);           // b' * conj(W)
        cpx t1 = cmul_cj(b1, tw[s]);
        x0 = up ? csub(a0, t0) : cadd(a0, t0);
        x1 = up ? csub(a1, t1) : cadd(a1, t1);
        d <<= 1;
    }
    // final intra-lane stage d=64 + 1/128 scaling
    cpx t = cmul_cj(x1, tw[0]);
    cpx a = x0;
    const float inv = 0.0078125f;  // 1/128
    x0 = { (a.re + t.re) * inv, (a.im + t.im) * inv };
    x1 = { (a.re - t.re) * inv, (a.im - t.im) * inv };
}

// ---------------------------------------------------------------------------
// fp32 SGEMM: C[M,N] = A[M,K] * B[K,N], all row-major, M%128==N%128==K%8==0.
// 128x128 tile, BK=8, 256 threads, 8x8 micro-tile per thread.
// ---------------------------------------------------------------------------
__global__ __launch_bounds__(256) void sgemm128(const float* __restrict__ A,
                                                const float* __restrict__ Bm,
                                                float* __restrict__ C,
                                                int M, int N, int K)
{
    __shared__ __align__(16) float As[8][128];   // [k][m] (transposed)
    __shared__ __align__(16) float Bs[8][128];   // [k][n]
    const int tid = threadIdx.x;
    const int bx = blockIdx.x;   // N tile
    const int by = blockIdx.y;   // M tile

    const int arow = tid >> 1;            // 0..127
    const int acol = (tid & 1) << 2;      // 0 or 4 (k offset)
    const int brow = tid >> 5;            // 0..7  (k offset)
    const int bcol = (tid & 31) << 2;     // 0..124

    const int tx = tid & 15;              // col group
    const int ty = tid >> 4;              // row group

    const float* Aptr = A + (size_t)(by * 128 + arow) * K + acol;
    const float* Bptr = Bm + (size_t)brow * N + bx * 128 + bcol;

    float acc[8][8];
#pragma unroll
    for (int i = 0; i < 8; ++i)
#pragma unroll
        for (int j = 0; j < 8; ++j) acc[i][j] = 0.f;

    for (int kt = 0; kt < K; kt += 8) {
        float4 av = *reinterpret_cast<const float4*>(Aptr + kt);
        float4 bv = *reinterpret_cast<const float4*>(Bptr + (size_t)kt * N);
        As[acol + 0][arow] = av.x;
        As[acol + 1][arow] = av.y;
        As[acol + 2][arow] = av.z;
        As[acol + 3][arow] = av.w;
        *reinterpret_cast<float4*>(&Bs[brow][bcol]) = bv;
        __syncthreads();
#pragma unroll
        for (int k = 0; k < 8; ++k) {
            float a[8], bb[8];
            *reinterpret_cast<float4*>(&a[0]) = *reinterpret_cast<const float4*>(&As[k][ty * 4]);
            *reinterpret_cast<float4*>(&a[4]) = *reinterpret_cast<const float4*>(&As[k][64 + ty * 4]);
            *reinterpret_cast<float4*>(&bb[0]) = *reinterpret_cast<const float4*>(&Bs[k][tx * 4]);
            *reinterpret_cast<float4*>(&bb[4]) = *reinterpret_cast<const float4*>(&Bs[k][64 + tx * 4]);
#pragma unroll
            for (int i = 0; i < 8; ++i)
#pragma unroll
                for (int j = 0; j < 8; ++j)
                    acc[i][j] = fmaf(a[i], bb[j], acc[i][j]);
        }
        __syncthreads();
    }

#pragma unroll
    for (int ih = 0; ih < 2; ++ih) {
#pragma unroll
        for (int i = 0; i < 4; ++i) {
            const int row = by * 128 + ih * 64 + ty * 4 + i;
            float* cp = C + (size_t)row * N + bx * 128;
            float4 c0 = { acc[ih * 4 + i][0], acc[ih * 4 + i][1],
                          acc[ih * 4 + i][2], acc[ih * 4 + i][3] };
            float4 c1 = { acc[ih * 4 + i][4], acc[ih * 4 + i][5],
                          acc[ih * 4 + i][6], acc[ih * 4 + i][7] };
            *reinterpret_cast<float4*>(cp + tx * 4) = c0;
            *reinterpret_cast<float4*>(cp + 64 + tx * 4) = c1;
        }
    }
}

// Same SGEMM but A is bf16 (vals buffer). B and C are fp32.
__global__ __launch_bounds__(256) void sgemm128_bf16A(const unsigned short* __restrict__ A,
                                                      const float* __restrict__ Bm,
                                                      float* __restrict__ C,
                                                      int M, int N, int K)
{
    __shared__ __align__(16) float As[8][128];   // [k][m] (transposed)
    __shared__ __align__(16) float Bs[8][128];   // [k][n]
    const int tid = threadIdx.x;
    const int bx = blockIdx.x;
    const int by = blockIdx.y;

    const int arow = tid >> 1;
    const int acol = (tid & 1) << 2;
    const int brow = tid >> 5;
    const int bcol = (tid & 31) << 2;

    const int tx = tid & 15;
    const int ty = tid >> 4;

    const unsigned short* Aptr = A + (size_t)(by * 128 + arow) * K + acol;
    const float* Bptr = Bm + (size_t)brow * N + bx * 128 + bcol;

    float acc[8][8];
#pragma unroll
    for (int i = 0; i < 8; ++i)
#pragma unroll
        for (int j = 0; j < 8; ++j) acc[i][j] = 0.f;

    for (int kt = 0; kt < K; kt += 8) {
        ushort4 av = *reinterpret_cast<const ushort4*>(Aptr + kt);
        float4 bv = *reinterpret_cast<const float4*>(Bptr + (size_t)kt * N);
        As[acol + 0][arow] = bf2f(av.x);
        As[acol + 1][arow] = bf2f(av.y);
        As[acol + 2][arow] = bf2f(av.z);
        As[acol + 3][arow] = bf2f(av.w);
        *reinterpret_cast<float4*>(&Bs[brow][bcol]) = bv;
        __syncthreads();
#pragma unroll
        for (int k = 0; k < 8; ++k) {
            float a[8], bb[8];
            *reinterpret_cast<float4*>(&a[0]) = *reinterpret_cast<const float4*>(&As[k][ty * 4]);
            *reinterpret_cast<float4*>(&a[4]) = *reinterpret_cast<const float4*>(&As[k][64 + ty * 4]);
            *reinterpret_cast<float4*>(&bb[0]) = *reinterpret_cast<const float4*>(&Bs[k][tx * 4]);
            *reinterpret_cast<float4*>(&bb[4]) = *reinterpret_cast<const float4*>(&Bs[k][64 + tx * 4]);
#pragma unroll
            for (int i = 0; i < 8; ++i)
#pragma unroll
                for (int j = 0; j < 8; ++j)
                    acc[i][j] = fmaf(a[i], bb[j], acc[i][j]);
        }
        __syncthreads();
    }

#pragma unroll
    for (int ih = 0; ih < 2; ++ih) {
#pragma unroll
        for (int i = 0; i < 4; ++i) {
            const int row = by * 128 + ih * 64 + ty * 4 + i;
            float* cp = C + (size_t)row * N + bx * 128;
            float4 c0 = { acc[ih * 4 + i][0], acc[ih * 4 + i][1],
                          acc[ih * 4 + i][2], acc[ih * 4 + i][3] };
            float4 c1 = { acc[ih * 4 + i][4], acc[ih * 4 + i][5],
                          acc[ih * 4 + i][6], acc[ih * 4 + i][7] };
            *reinterpret_cast<float4*>(cp + tx * 4) = c0;
            *reinterpret_cast<float4*>(cp + 64 + tx * 4) = c1;
        }
    }
}

// ---------------------------------------------------------------------------
// Phase A: per (b,h,chunk) compute T = sum over chunk of FFT(k)*FFT(v)
// (in the FFT's permuted bin order). totals layout: [bh][chunk][256 floats],
// component index = (slot*64 + lane)*2 + {re,im}.
// ---------------------------------------------------------------------------
__global__ __launch_bounds__(256) void hrr_phaseA(const float* __restrict__ qkv,
                                                  float* __restrict__ totals)
{
    const int blk = blockIdx.x;
    const int bh = blk / NCHUNK;
    const int chunk = blk % NCHUNK;
    const int b = bh >> 3, h = bh & 7;
    const int tid = threadIdx.x;
    const int wave = tid >> 6, lane = tid & 63;

    cpx tw[7];
    make_tw(lane, tw);

    cpx acc0 = {0.f, 0.f}, acc1 = {0.f, 0.f};
    const int s0 = chunk * CS + wave * (CS / 4);
    for (int i = 0; i < CS / 4; ++i) {
        const int s = s0 + i;
        const float* base = qkv + (size_t)(b * SS + s) * 3072 + h * 128;
        cpx k0 = { base[1024 + lane], 0.f };
        cpx k1 = { base[1024 + 64 + lane], 0.f };
        cpx v0 = { base[2048 + lane], 0.f };
        cpx v1 = { base[2048 + 64 + lane], 0.f };
        fft128_fwd(k0, k1, tw, lane);
        fft128_fwd(v0, v1, tw, lane);
        acc0 = cadd(acc0, cmul(k0, v0));
        acc1 = cadd(acc1, cmul(k1, v1));
    }

    __shared__ float red[4][256];
    red[wave][lane * 2 + 0] = acc0.re;
    red[wave][lane * 2 + 1] = acc0.im;
    red[wave][128 + lane * 2 + 0] = acc1.re;
    red[wave][128 + lane * 2 + 1] = acc1.im;
    __syncthreads();

    float s4 = red[0][tid] + red[1][tid] + red[2][tid] + red[3][tid];
    totals[((size_t)bh * NCHUNK + chunk) * 256 + tid] = s4;
}

// ---------------------------------------------------------------------------
// Phase B: in-place exclusive scan of chunk totals over the chunk axis,
// independently per (bh, component). 32 blocks x 256 threads.
// ---------------------------------------------------------------------------
__global__ __launch_bounds__(256) void hrr_phaseB(float* __restrict__ totals)
{
    const int bh = blockIdx.x;
    const int t = threadIdx.x;
    float run = 0.f;
    for (int c = 0; c < NCHUNK; ++c) {
        const size_t idx = ((size_t)bh * NCHUNK + c) * 256 + t;
        float v = totals[idx];
        totals[idx] = run;
        run += v;
    }
}

// ---------------------------------------------------------------------------
// Phase C: recompute P per position into LDS, inclusive scan within chunk
// (seeded by the exclusive chunk offset), unbind with conj(FFT(q)), IFFT,
// write real part (as bf16) to vals [B,S,D].
// ---------------------------------------------------------------------------
__global__ __launch_bounds__(256) void hrr_phaseC(const float* __restrict__ qkv,
                                                  const float* __restrict__ totals,
                                                  unsigned short* __restrict__ vals)
{
    __shared__ float Pf[CS * 256];   // 64 KB: [s_local][component]

    const int blk = blockIdx.x;
    const int bh = blk / NCHUNK;
    const int chunk = blk % NCHUNK;
    const int b = bh >> 3, h = bh & 7;
    const int tid = threadIdx.x;
    const int wave = tid >> 6, lane = tid & 63;

    cpx tw[7];
    make_tw(lane, tw);

    // Pass 1: P = FFT(k) * FFT(v) for each position in the chunk -> LDS
    for (int i = 0; i < CS / 4; ++i) {
        const int sl = wave * (CS / 4) + i;
        const int s = chunk * CS + sl;
        const float* base = qkv + (size_t)(b * SS + s) * 3072 + h * 128;
        cpx k0 = { base[1024 + lane], 0.f };
        cpx k1 = { base[1024 + 64 + lane], 0.f };
        cpx v0 = { base[2048 + lane], 0.f };
        cpx v1 = { base[2048 + 64 + lane], 0.f };
        fft128_fwd(k0, k1, tw, lane);
        fft128_fwd(v0, v1, tw, lane);
        cpx p0 = cmul(k0, v0);
        cpx p1 = cmul(k1, v1);
        float* row = &Pf[sl * 256];
        row[lane * 2 + 0] = p0.re;
        row[lane * 2 + 1] = p0.im;
        row[128 + lane * 2 + 0] = p1.re;
        row[128 + lane * 2 + 1] = p1.im;
    }
    __syncthreads();

    // Pass 2: component-parallel inclusive scan over the chunk
    {
        float run = totals[((size_t)bh * NCHUNK + chunk) * 256 + tid];
#pragma unroll 8
        for (int s = 0; s < CS; ++s) {
            run += Pf[s * 256 + tid];
            Pf[s * 256 + tid] = run;
        }
    }
    __syncthreads();

    // Pass 3: unbind with conj(FFT(q)), inverse FFT, store real part (bf16)
    for (int i = 0; i < CS / 4; ++i) {
        const int sl = wave * (CS / 4) + i;
        const int s = chunk * CS + sl;
        const float* base = qkv + (size_t)(b * SS + s) * 3072 + h * 128;
        cpx q0 = { base[lane], 0.f };
        cpx q1 = { base[64 + lane], 0.f };
        fft128_fwd(q0, q1, tw, lane);
        const float* row = &Pf[sl * 256];
        cpx c0 = { row[lane * 2 + 0], row[lane * 2 + 1] };
        cpx c1 = { row[128 + lane * 2 + 0], row[128 + lane * 2 + 1] };
        cpx u0 = cmul_cj(c0, q0);
        cpx u1 = cmul_cj(c1, q1);
        fft128_inv(u0, u1, tw, lane);
        unsigned short* o = vals + (size_t)(b * SS + s) * DD + h * 128;
        o[lane] = f2bf(u0.re);
        o[64 + lane] = f2bf(u1.re);
    }
}

// ---------------------------------------------------------------------------
// Launch
// ---------------------------------------------------------------------------
extern "C" void kernel_launch(void* const* d_in, const int* in_sizes, int n_in,
                              void* d_out, int out_size, void* d_ws, size_t ws_size,
                              hipStream_t stream) {
    const float* x     = (const float*)d_in[0];   // [B,S,D]
    const float* w_qkv = (const float*)d_in[1];   // [D, 3D]
    const float* w_out = (const float*)d_in[2];   // [D, D]
    float* out = (float*)d_out;                   // [B,S,D]

    // Workspace layout (~237 MB total):
    //   qkv    fp32 [16384, 3072]   201.3 MB
    //   vals   bf16 [16384, 1024]    33.6 MB
    //   totals fp32 [32, 64, 256]     2.1 MB
    float* qkv = (float*)d_ws;
    unsigned short* vals = (unsigned short*)(qkv + (size_t)MROWS * 3072);
    float* totals = (float*)(vals + (size_t)MROWS * DD);

    // 1) qkv = x @ w_qkv
    sgemm128<<<dim3(3072 / 128, MROWS / 128), 256, 0, stream>>>(
        x, w_qkv, qkv, MROWS, 3072, DD);

    // 2) chunk totals of FK*FV
    hrr_phaseA<<<BB * HH * NCHUNK, 256, 0, stream>>>(qkv, totals);

    // 3) exclusive scan of chunk totals
    hrr_phaseB<<<BB * HH, 256, 0, stream>>>(totals);

    // 4) in-chunk scan + unbind + inverse FFT -> vals (bf16)
    hrr_phaseC<<<BB * HH * NCHUNK, 256, 0, stream>>>(qkv, totals, vals);

    // 5) out = vals @ w_out
    sgemm128_bf16A<<<dim3(DD / 128, MROWS / 128), 256, 0, stream>>>(
        vals, w_out, out, MROWS, DD, DD);
}

// Round 3
// 762.678 us; speedup vs baseline: 2.5607x; 2.5607x over previous
//
#include <hip/hip_runtime.h>

// Problem constants
static constexpr int BB = 4;
static constexpr int SS = 4096;
static constexpr int DD = 1024;
static constexpr int HH = 8;
static constexpr int HD = 128;     // FFT length
static constexpr int CS = 64;      // scan chunk size (positions per block)
static constexpr int NCHUNK = SS / CS;   // 64
static constexpr int MROWS = BB * SS;    // 16384

typedef __attribute__((ext_vector_type(8))) short bfrag;    // 8 bf16 (4 VGPRs)
typedef __attribute__((ext_vector_type(4))) float floatx4;  // MFMA acc

// ---------------------------------------------------------------------------
// bf16 helpers
// ---------------------------------------------------------------------------
__device__ __forceinline__ float bf2f(unsigned short u) {
    unsigned int x = ((unsigned int)u) << 16;
    return __uint_as_float(x);
}
__device__ __forceinline__ unsigned short f2bf(float f) {  // RNE
    unsigned int x = __float_as_uint(f);
    unsigned int r = x + 0x7FFFu + ((x >> 16) & 1u);
    return (unsigned short)(r >> 16);
}
__device__ __forceinline__ unsigned int pack_rne(float a, float b) {
    return ((unsigned int)f2bf(a)) | (((unsigned int)f2bf(b)) << 16);
}

// async global->LDS, 16B per lane; LDS dest = wave-uniform base + lane*16
__device__ __forceinline__ void async_copy16(const void* g, void* l) {
    __builtin_amdgcn_global_load_lds(
        (const __attribute__((address_space(1))) unsigned int*)g,
        (__attribute__((address_space(3))) unsigned int*)l, 16, 0, 0);
}

// ---------------------------------------------------------------------------
// Complex helpers
// ---------------------------------------------------------------------------
struct cpx { float re, im; };

__device__ __forceinline__ cpx cadd(cpx a, cpx b) { return {a.re + b.re, a.im + b.im}; }
__device__ __forceinline__ cpx csub(cpx a, cpx b) { return {a.re - b.re, a.im - b.im}; }
__device__ __forceinline__ cpx cmul(cpx a, cpx b) {
    return { fmaf(a.re, b.re, -a.im * b.im), fmaf(a.re, b.im, a.im * b.re) };
}
__device__ __forceinline__ cpx cmul_cj(cpx a, cpx b) {   // a * conj(b)
    return { fmaf(a.re, b.re, a.im * b.im), fmaf(a.im, b.re, -a.re * b.im) };
}
__device__ __forceinline__ cpx shflx(cpx x, int m) {
    return { __shfl_xor(x.re, m), __shfl_xor(x.im, m) };
}

__device__ __forceinline__ void make_tw(int lane, cpx tw[7]) {
    const float NEG2PI = -6.28318530717958647692f;
    float a0 = NEG2PI * (float)lane * (1.0f / 128.0f);
    tw[0] = { __cosf(a0), __sinf(a0) };
    int d = 32;
#pragma unroll
    for (int s = 1; s <= 6; ++s) {
        int i = lane & (d - 1);
        float a = NEG2PI * (float)i / (float)(2 * d);
        tw[s] = { __cosf(a), __sinf(a) };
        d >>= 1;
    }
}

__device__ __forceinline__ void fft128_fwd(cpx& x0, cpx& x1, const cpx tw[7], int lane) {
    cpx a = x0, b = x1;
    x0 = cadd(a, b);
    x1 = cmul(csub(a, b), tw[0]);
    int d = 32;
#pragma unroll
    for (int s = 1; s <= 6; ++s) {
        const bool up = (lane & d) != 0;
        cpx o0 = shflx(x0, d);
        cpx o1 = shflx(x1, d);
        cpx s0 = cadd(x0, o0);
        cpx s1 = cadd(x1, o1);
        cpx d0 = cmul(csub(o0, x0), tw[s]);
        cpx d1 = cmul(csub(o1, x1), tw[s]);
        x0 = up ? d0 : s0;
        x1 = up ? d1 : s1;
        d >>= 1;
    }
}

__device__ __forceinline__ void fft128_inv(cpx& x0, cpx& x1, const cpx tw[7], int lane) {
    int d = 1;
#pragma unroll
    for (int s = 6; s >= 1; --s) {
        const bool up = (lane & d) != 0;
        cpx o0 = shflx(x0, d);
        cpx o1 = shflx(x1, d);
        cpx b0 = up ? x0 : o0;
        cpx a0 = up ? o0 : x0;
        cpx b1 = up ? x1 : o1;
        cpx a1 = up ? o1 : x1;
        cpx t0 = cmul_cj(b0, tw[s]);
        cpx t1 = cmul_cj(b1, tw[s]);
        x0 = up ? csub(a0, t0) : cadd(a0, t0);
        x1 = up ? csub(a1, t1) : cadd(a1, t1);
        d <<= 1;
    }
    cpx t = cmul_cj(x1, tw[0]);
    cpx a = x0;
    const float inv = 0.0078125f;
    x0 = { (a.re + t.re) * inv, (a.im + t.im) * inv };
    x1 = { (a.re - t.re) * inv, (a.im - t.im) * inv };
}

// ---------------------------------------------------------------------------
// Transpose + bf16 split: W fp32 [K,N] -> Th,Tl bf16 [N,K]
// (trunc high + residual; Th+Tl reproduces W to ~2^-16 relative)
// ---------------------------------------------------------------------------
__global__ __launch_bounds__(256) void transpose_split(const float* __restrict__ W,
                                                       unsigned short* __restrict__ Th,
                                                       unsigned short* __restrict__ Tl,
                                                       int K, int N)
{
    __shared__ float tile[32][33];
    const int n0 = blockIdx.x * 32, k0 = blockIdx.y * 32;
    const int r = threadIdx.x >> 5, c = threadIdx.x & 31;
#pragma unroll
    for (int i = 0; i < 4; ++i)
        tile[r + 8 * i][c] = W[(size_t)(k0 + r + 8 * i) * N + n0 + c];
    __syncthreads();
#pragma unroll
    for (int i = 0; i < 4; ++i) {
        float v = tile[c][r + 8 * i];
        unsigned int u = __float_as_uint(v);
        unsigned short h = (unsigned short)(u >> 16);
        float resid = v - __uint_as_float(u & 0xFFFF0000u);
        unsigned short l = (unsigned short)(__float_as_uint(resid) >> 16);
        const size_t o = (size_t)(n0 + r + 8 * i) * K + k0 + c;
        Th[o] = h;
        Tl[o] = l;
    }
}

// Transpose + RNE bf16: W fp32 [K,N] -> T bf16 [N,K]
__global__ __launch_bounds__(256) void transpose_rn(const float* __restrict__ W,
                                                    unsigned short* __restrict__ T,
                                                    int K, int N)
{
    __shared__ float tile[32][33];
    const int n0 = blockIdx.x * 32, k0 = blockIdx.y * 32;
    const int r = threadIdx.x >> 5, c = threadIdx.x & 31;
#pragma unroll
    for (int i = 0; i < 4; ++i)
        tile[r + 8 * i][c] = W[(size_t)(k0 + r + 8 * i) * N + n0 + c];
    __syncthreads();
#pragma unroll
    for (int i = 0; i < 4; ++i) {
        float v = tile[c][r + 8 * i];
        T[(size_t)(n0 + r + 8 * i) * K + k0 + c] = f2bf(v);
    }
}

// ---------------------------------------------------------------------------
// GEMM1: C[M,N] = A[M,K](fp32, converted to bf16 RNE in staging) *
//        (Bh+Bl)[N,K]^T (split bf16). 128x128 tile, BK=32, 256 threads,
//        4 waves each 64x64 via 4x4 of 16x16x32 MFMA, 2 MFMAs per tile (hi+lo B).
// ---------------------------------------------------------------------------
__global__ __launch_bounds__(256) void gemm_x_wsplit(const float* __restrict__ A,
                                                     const unsigned short* __restrict__ Bh,
                                                     const unsigned short* __restrict__ Bl,
                                                     float* __restrict__ C,
                                                     int M, int N, int K)
{
    __shared__ __align__(16) unsigned short As[128 * 32];
    __shared__ __align__(16) unsigned short Bhs[128 * 32];
    __shared__ __align__(16) unsigned short Bls[128 * 32];
    const int tid = threadIdx.x, lane = tid & 63, w = tid >> 6;
    const int wr = w >> 1, wc = w & 1;
    const int m0 = blockIdx.y * 128, n0 = blockIdx.x * 128;
    const int arow = tid >> 1, akh = (tid & 1) * 16;

    floatx4 acc[4][4];
#pragma unroll
    for (int i = 0; i < 4; ++i)
#pragma unroll
        for (int j = 0; j < 4; ++j) { floatx4 z = {0.f, 0.f, 0.f, 0.f}; acc[i][j] = z; }

    for (int kt = 0; kt < K; kt += 32) {
        // B staging: async copy both hi and lo tiles (8 issues each across block)
#pragma unroll
        for (int i = 0; i < 2; ++i) {
            const int is = 2 * w + i;
            const size_t boff = (size_t)(n0 + 16 * is + (lane >> 2)) * K + kt + (lane & 3) * 8;
            async_copy16(Bh + boff, &Bhs[512 * is]);
            async_copy16(Bl + boff, &Bls[512 * is]);
        }
        // A staging: fp32 load + RNE bf16 convert + LDS write (16 elems/thread)
        const float* ga = A + (size_t)(m0 + arow) * K + kt + akh;
        float4 v0 = *reinterpret_cast<const float4*>(ga + 0);
        float4 v1 = *reinterpret_cast<const float4*>(ga + 4);
        float4 v2 = *reinterpret_cast<const float4*>(ga + 8);
        float4 v3 = *reinterpret_cast<const float4*>(ga + 12);
        uint4 pa = { pack_rne(v0.x, v0.y), pack_rne(v0.z, v0.w),
                     pack_rne(v1.x, v1.y), pack_rne(v1.z, v1.w) };
        uint4 pb = { pack_rne(v2.x, v2.y), pack_rne(v2.z, v2.w),
                     pack_rne(v3.x, v3.y), pack_rne(v3.z, v3.w) };
        *reinterpret_cast<uint4*>(&As[arow * 32 + akh]) = pa;
        *reinterpret_cast<uint4*>(&As[arow * 32 + akh + 8]) = pb;
        __syncthreads();

        bfrag af[4], bh_[4], bl_[4];
#pragma unroll
        for (int t = 0; t < 4; ++t)
            af[t] = *reinterpret_cast<const bfrag*>(
                &As[(64 * wr + 16 * t + (lane & 15)) * 32 + (lane >> 4) * 8]);
#pragma unroll
        for (int t = 0; t < 4; ++t) {
            const int off = (64 * wc + 16 * t + (lane & 15)) * 32 + (lane >> 4) * 8;
            bh_[t] = *reinterpret_cast<const bfrag*>(&Bhs[off]);
            bl_[t] = *reinterpret_cast<const bfrag*>(&Bls[off]);
        }
#pragma unroll
        for (int i = 0; i < 4; ++i)
#pragma unroll
            for (int j = 0; j < 4; ++j) {
                acc[i][j] = __builtin_amdgcn_mfma_f32_16x16x32_bf16(af[i], bh_[j], acc[i][j], 0, 0, 0);
                acc[i][j] = __builtin_amdgcn_mfma_f32_16x16x32_bf16(af[i], bl_[j], acc[i][j], 0, 0, 0);
            }
        __syncthreads();
    }

#pragma unroll
    for (int i = 0; i < 4; ++i)
#pragma unroll
        for (int j = 0; j < 4; ++j)
#pragma unroll
            for (int r = 0; r < 4; ++r) {
                const int row = m0 + 64 * wr + 16 * i + (lane >> 4) * 4 + r;
                const int col = n0 + 64 * wc + 16 * j + (lane & 15);
                C[(size_t)row * N + col] = acc[i][j][r];
            }
}

// ---------------------------------------------------------------------------
// GEMM2: C[M,N] = A[M,K](bf16) * Bt[N,K]^T(bf16). Pure m97 structure:
// both tiles staged with global_load_lds width=16.
// ---------------------------------------------------------------------------
__global__ __launch_bounds__(256) void gemm_bt_bf16(const unsigned short* __restrict__ A,
                                                    const unsigned short* __restrict__ Bt,
                                                    float* __restrict__ C,
                                                    int M, int N, int K)
{
    __shared__ __align__(16) unsigned short As[128 * 32];
    __shared__ __align__(16) unsigned short Bs[128 * 32];
    const int tid = threadIdx.x, lane = tid & 63, w = tid >> 6;
    const int wr = w >> 1, wc = w & 1;
    const int m0 = blockIdx.y * 128, n0 = blockIdx.x * 128;

    floatx4 acc[4][4];
#pragma unroll
    for (int i = 0; i < 4; ++i)
#pragma unroll
        for (int j = 0; j < 4; ++j) { floatx4 z = {0.f, 0.f, 0.f, 0.f}; acc[i][j] = z; }

    for (int kt = 0; kt < K; kt += 32) {
#pragma unroll
        for (int i = 0; i < 2; ++i) {
            const int is = 2 * w + i;
            const size_t aoff = (size_t)(m0 + 16 * is + (lane >> 2)) * K + kt + (lane & 3) * 8;
            const size_t boff = (size_t)(n0 + 16 * is + (lane >> 2)) * K + kt + (lane & 3) * 8;
            async_copy16(A + aoff, &As[512 * is]);
            async_copy16(Bt + boff, &Bs[512 * is]);
        }
        __syncthreads();

        bfrag af[4], bf_[4];
#pragma unroll
        for (int t = 0; t < 4; ++t)
            af[t] = *reinterpret_cast<const bfrag*>(
                &As[(64 * wr + 16 * t + (lane & 15)) * 32 + (lane >> 4) * 8]);
#pragma unroll
        for (int t = 0; t < 4; ++t)
            bf_[t] = *reinterpret_cast<const bfrag*>(
                &Bs[(64 * wc + 16 * t + (lane & 15)) * 32 + (lane >> 4) * 8]);
#pragma unroll
        for (int i = 0; i < 4; ++i)
#pragma unroll
            for (int j = 0; j < 4; ++j)
                acc[i][j] = __builtin_amdgcn_mfma_f32_16x16x32_bf16(af[i], bf_[j], acc[i][j], 0, 0, 0);
        __syncthreads();
    }

#pragma unroll
    for (int i = 0; i < 4; ++i)
#pragma unroll
        for (int j = 0; j < 4; ++j)
#pragma unroll
            for (int r = 0; r < 4; ++r) {
                const int row = m0 + 64 * wr + 16 * i + (lane >> 4) * 4 + r;
                const int col = n0 + 64 * wc + 16 * j + (lane & 15);
                C[(size_t)row * N + col] = acc[i][j][r];
            }
}

// ---------------------------------------------------------------------------
// Phase A: per (b,h,chunk) totals of FFT(k)*FFT(v)
// ---------------------------------------------------------------------------
__global__ __launch_bounds__(256) void hrr_phaseA(const float* __restrict__ qkv,
                                                  float* __restrict__ totals)
{
    const int blk = blockIdx.x;
    const int bh = blk / NCHUNK;
    const int chunk = blk % NCHUNK;
    const int b = bh >> 3, h = bh & 7;
    const int tid = threadIdx.x;
    const int wave = tid >> 6, lane = tid & 63;

    cpx tw[7];
    make_tw(lane, tw);

    cpx acc0 = {0.f, 0.f}, acc1 = {0.f, 0.f};
    const int s0 = chunk * CS + wave * (CS / 4);
    for (int i = 0; i < CS / 4; ++i) {
        const int s = s0 + i;
        const float* base = qkv + (size_t)(b * SS + s) * 3072 + h * 128;
        cpx k0 = { base[1024 + lane], 0.f };
        cpx k1 = { base[1024 + 64 + lane], 0.f };
        cpx v0 = { base[2048 + lane], 0.f };
        cpx v1 = { base[2048 + 64 + lane], 0.f };
        fft128_fwd(k0, k1, tw, lane);
        fft128_fwd(v0, v1, tw, lane);
        acc0 = cadd(acc0, cmul(k0, v0));
        acc1 = cadd(acc1, cmul(k1, v1));
    }

    __shared__ float red[4][256];
    red[wave][lane * 2 + 0] = acc0.re;
    red[wave][lane * 2 + 1] = acc0.im;
    red[wave][128 + lane * 2 + 0] = acc1.re;
    red[wave][128 + lane * 2 + 1] = acc1.im;
    __syncthreads();

    float s4 = red[0][tid] + red[1][tid] + red[2][tid] + red[3][tid];
    totals[((size_t)bh * NCHUNK + chunk) * 256 + tid] = s4;
}

// ---------------------------------------------------------------------------
// Phase B: exclusive scan of chunk totals
// ---------------------------------------------------------------------------
__global__ __launch_bounds__(256) void hrr_phaseB(float* __restrict__ totals)
{
    const int bh = blockIdx.x;
    const int t = threadIdx.x;
    float run = 0.f;
    for (int c = 0; c < NCHUNK; ++c) {
        const size_t idx = ((size_t)bh * NCHUNK + c) * 256 + t;
        float v = totals[idx];
        totals[idx] = run;
        run += v;
    }
}

// ---------------------------------------------------------------------------
// Phase C: in-chunk scan + unbind + inverse FFT -> vals (bf16)
// ---------------------------------------------------------------------------
__global__ __launch_bounds__(256) void hrr_phaseC(const float* __restrict__ qkv,
                                                  const float* __restrict__ totals,
                                                  unsigned short* __restrict__ vals)
{
    __shared__ float Pf[CS * 256];   // 64 KB

    const int blk = blockIdx.x;
    const int bh = blk / NCHUNK;
    const int chunk = blk % NCHUNK;
    const int b = bh >> 3, h = bh & 7;
    const int tid = threadIdx.x;
    const int wave = tid >> 6, lane = tid & 63;

    cpx tw[7];
    make_tw(lane, tw);

    for (int i = 0; i < CS / 4; ++i) {
        const int sl = wave * (CS / 4) + i;
        const int s = chunk * CS + sl;
        const float* base = qkv + (size_t)(b * SS + s) * 3072 + h * 128;
        cpx k0 = { base[1024 + lane], 0.f };
        cpx k1 = { base[1024 + 64 + lane], 0.f };
        cpx v0 = { base[2048 + lane], 0.f };
        cpx v1 = { base[2048 + 64 + lane], 0.f };
        fft128_fwd(k0, k1, tw, lane);
        fft128_fwd(v0, v1, tw, lane);
        cpx p0 = cmul(k0, v0);
        cpx p1 = cmul(k1, v1);
        float* row = &Pf[sl * 256];
        row[lane * 2 + 0] = p0.re;
        row[lane * 2 + 1] = p0.im;
        row[128 + lane * 2 + 0] = p1.re;
        row[128 + lane * 2 + 1] = p1.im;
    }
    __syncthreads();

    {
        float run = totals[((size_t)bh * NCHUNK + chunk) * 256 + tid];
#pragma unroll 8
        for (int s = 0; s < CS; ++s) {
            run += Pf[s * 256 + tid];
            Pf[s * 256 + tid] = run;
        }
    }
    __syncthreads();

    for (int i = 0; i < CS / 4; ++i) {
        const int sl = wave * (CS / 4) + i;
        const int s = chunk * CS + sl;
        const float* base = qkv + (size_t)(b * SS + s) * 3072 + h * 128;
        cpx q0 = { base[lane], 0.f };
        cpx q1 = { base[64 + lane], 0.f };
        fft128_fwd(q0, q1, tw, lane);
        const float* row = &Pf[sl * 256];
        cpx c0 = { row[lane * 2 + 0], row[lane * 2 + 1] };
        cpx c1 = { row[128 + lane * 2 + 0], row[128 + lane * 2 + 1] };
        cpx u0 = cmul_cj(c0, q0);
        cpx u1 = cmul_cj(c1, q1);
        fft128_inv(u0, u1, tw, lane);
        unsigned short* o = vals + (size_t)(b * SS + s) * DD + h * 128;
        o[lane] = f2bf(u0.re);
        o[64 + lane] = f2bf(u1.re);
    }
}

// ---------------------------------------------------------------------------
// Launch
// ---------------------------------------------------------------------------
extern "C" void kernel_launch(void* const* d_in, const int* in_sizes, int n_in,
                              void* d_out, int out_size, void* d_ws, size_t ws_size,
                              hipStream_t stream) {
    const float* x     = (const float*)d_in[0];   // [B,S,D]
    const float* w_qkv = (const float*)d_in[1];   // [D, 3D]
    const float* w_out = (const float*)d_in[2];   // [D, D]
    float* out = (float*)d_out;                   // [B,S,D]

    // Workspace layout (251.7 MB total):
    //   qkv     fp32 [16384,3072]  201.3 MB
    //   vals    bf16 [16384,1024]   33.6 MB
    //   totals  fp32 [32,64,256]     2.1 MB
    //   wqkvt_h bf16 [3072,1024]     6.3 MB
    //   wqkvt_l bf16 [3072,1024]     6.3 MB
    //   woutt   bf16 [1024,1024]     2.1 MB
    float* qkv = (float*)d_ws;
    unsigned short* vals = (unsigned short*)(qkv + (size_t)MROWS * 3072);
    float* totals = (float*)(vals + (size_t)MROWS * DD);
    unsigned short* wqkvt_h = (unsigned short*)(totals + (size_t)32 * 64 * 256);
    unsigned short* wqkvt_l = wqkvt_h + (size_t)3072 * 1024;
    unsigned short* woutt   = wqkvt_l + (size_t)3072 * 1024;

    // 0) weight prep: transpose + bf16 (split for w_qkv, RNE for w_out)
    transpose_split<<<dim3(3072 / 32, 1024 / 32), 256, 0, stream>>>(
        w_qkv, wqkvt_h, wqkvt_l, 1024, 3072);
    transpose_rn<<<dim3(1024 / 32, 1024 / 32), 256, 0, stream>>>(
        w_out, woutt, 1024, 1024);

    // 1) qkv = x @ w_qkv  (split-B MFMA, near-fp32 accuracy in w)
    gemm_x_wsplit<<<dim3(3072 / 128, MROWS / 128), 256, 0, stream>>>(
        x, wqkvt_h, wqkvt_l, qkv, MROWS, 3072, DD);

    // 2) chunk totals of FK*FV
    hrr_phaseA<<<BB * HH * NCHUNK, 256, 0, stream>>>(qkv, totals);

    // 3) exclusive scan of chunk totals
    hrr_phaseB<<<BB * HH, 256, 0, stream>>>(totals);

    // 4) in-chunk scan + unbind + inverse FFT -> vals (bf16)
    hrr_phaseC<<<BB * HH * NCHUNK, 256, 0, stream>>>(qkv, totals, vals);

    // 5) out = vals @ w_out  (plain bf16 MFMA)
    gemm_bt_bf16<<<dim3(DD / 128, MROWS / 128), 256, 0, stream>>>(
        vals, woutt, out, MROWS, DD, DD);
}

// Round 4
// 566.276 us; speedup vs baseline: 3.4488x; 1.3468x over previous
//
#include <hip/hip_runtime.h>

// Problem constants
static constexpr int BB = 4;
static constexpr int SS = 4096;
static constexpr int DD = 1024;
static constexpr int HH = 8;
static constexpr int HD = 128;     // FFT length
static constexpr int CS = 64;      // scan chunk size (positions per block)
static constexpr int NCHUNK = SS / CS;   // 64
static constexpr int MROWS = BB * SS;    // 16384

typedef __attribute__((ext_vector_type(8))) short bfrag;    // 8 bf16 (4 VGPRs)
typedef __attribute__((ext_vector_type(4))) float floatx4;  // MFMA acc

// ---------------------------------------------------------------------------
// bf16 helpers
// ---------------------------------------------------------------------------
__device__ __forceinline__ float bf2f(unsigned short u) {
    unsigned int x = ((unsigned int)u) << 16;
    return __uint_as_float(x);
}
__device__ __forceinline__ unsigned short f2bf(float f) {  // RNE
    unsigned int x = __float_as_uint(f);
    unsigned int r = x + 0x7FFFu + ((x >> 16) & 1u);
    return (unsigned short)(r >> 16);
}
__device__ __forceinline__ unsigned int pack_rne(float a, float b) {
    return ((unsigned int)f2bf(a)) | (((unsigned int)f2bf(b)) << 16);
}

// async global->LDS, 16B per lane; LDS dest = wave-uniform base + lane*16
__device__ __forceinline__ void async_copy16(const void* g, void* l) {
    __builtin_amdgcn_global_load_lds(
        (const __attribute__((address_space(1))) unsigned int*)g,
        (__attribute__((address_space(3))) unsigned int*)l, 16, 0, 0);
}

// ---------------------------------------------------------------------------
// Complex helpers
// ---------------------------------------------------------------------------
struct cpx { float re, im; };

__device__ __forceinline__ cpx cadd(cpx a, cpx b) { return {a.re + b.re, a.im + b.im}; }
__device__ __forceinline__ cpx csub(cpx a, cpx b) { return {a.re - b.re, a.im - b.im}; }
__device__ __forceinline__ cpx cmul(cpx a, cpx b) {
    return { fmaf(a.re, b.re, -a.im * b.im), fmaf(a.re, b.im, a.im * b.re) };
}
__device__ __forceinline__ cpx cmul_cj(cpx a, cpx b) {   // a * conj(b)
    return { fmaf(a.re, b.re, a.im * b.im), fmaf(a.im, b.re, -a.re * b.im) };
}
__device__ __forceinline__ cpx shflx(cpx x, int m) {
    return { __shfl_xor(x.re, m), __shfl_xor(x.im, m) };
}

__device__ __forceinline__ void make_tw(int lane, cpx tw[7]) {
    const float NEG2PI = -6.28318530717958647692f;
    float a0 = NEG2PI * (float)lane * (1.0f / 128.0f);
    tw[0] = { __cosf(a0), __sinf(a0) };
    int d = 32;
#pragma unroll
    for (int s = 1; s <= 6; ++s) {
        int i = lane & (d - 1);
        float a = NEG2PI * (float)i / (float)(2 * d);
        tw[s] = { __cosf(a), __sinf(a) };
        d >>= 1;
    }
}

__device__ __forceinline__ void fft128_fwd(cpx& x0, cpx& x1, const cpx tw[7], int lane) {
    cpx a = x0, b = x1;
    x0 = cadd(a, b);
    x1 = cmul(csub(a, b), tw[0]);
    int d = 32;
#pragma unroll
    for (int s = 1; s <= 6; ++s) {
        const bool up = (lane & d) != 0;
        cpx o0 = shflx(x0, d);
        cpx o1 = shflx(x1, d);
        cpx s0 = cadd(x0, o0);
        cpx s1 = cadd(x1, o1);
        cpx d0 = cmul(csub(o0, x0), tw[s]);
        cpx d1 = cmul(csub(o1, x1), tw[s]);
        x0 = up ? d0 : s0;
        x1 = up ? d1 : s1;
        d >>= 1;
    }
}

__device__ __forceinline__ void fft128_inv(cpx& x0, cpx& x1, const cpx tw[7], int lane) {
    int d = 1;
#pragma unroll
    for (int s = 6; s >= 1; --s) {
        const bool up = (lane & d) != 0;
        cpx o0 = shflx(x0, d);
        cpx o1 = shflx(x1, d);
        cpx b0 = up ? x0 : o0;
        cpx a0 = up ? o0 : x0;
        cpx b1 = up ? x1 : o1;
        cpx a1 = up ? o1 : x1;
        cpx t0 = cmul_cj(b0, tw[s]);
        cpx t1 = cmul_cj(b1, tw[s]);
        x0 = up ? csub(a0, t0) : cadd(a0, t0);
        x1 = up ? csub(a1, t1) : cadd(a1, t1);
        d <<= 1;
    }
    cpx t = cmul_cj(x1, tw[0]);
    cpx a = x0;
    const float inv = 0.0078125f;
    x0 = { (a.re + t.re) * inv, (a.im + t.im) * inv };
    x1 = { (a.re - t.re) * inv, (a.im - t.im) * inv };
}

// ---------------------------------------------------------------------------
// x fp32 -> bf16 (RNE), 8 elems/thread
// ---------------------------------------------------------------------------
__global__ __launch_bounds__(256) void convert_bf16(const float* __restrict__ X,
                                                    unsigned short* __restrict__ Y)
{
    const size_t i = ((size_t)blockIdx.x * 256 + threadIdx.x) * 8;
    float4 v0 = *reinterpret_cast<const float4*>(X + i);
    float4 v1 = *reinterpret_cast<const float4*>(X + i + 4);
    uint4 p = { pack_rne(v0.x, v0.y), pack_rne(v0.z, v0.w),
                pack_rne(v1.x, v1.y), pack_rne(v1.z, v1.w) };
    *reinterpret_cast<uint4*>(Y + i) = p;
}

// Transpose + RNE bf16: W fp32 [K,N] -> T bf16 [N,K]
__global__ __launch_bounds__(256) void transpose_rn(const float* __restrict__ W,
                                                    unsigned short* __restrict__ T,
                                                    int K, int N)
{
    __shared__ float tile[32][33];
    const int n0 = blockIdx.x * 32, k0 = blockIdx.y * 32;
    const int r = threadIdx.x >> 5, c = threadIdx.x & 31;
#pragma unroll
    for (int i = 0; i < 4; ++i)
        tile[r + 8 * i][c] = W[(size_t)(k0 + r + 8 * i) * N + n0 + c];
    __syncthreads();
#pragma unroll
    for (int i = 0; i < 4; ++i) {
        float v = tile[c][r + 8 * i];
        T[(size_t)(n0 + r + 8 * i) * K + k0 + c] = f2bf(v);
    }
}

// ---------------------------------------------------------------------------
// m97-style bf16 GEMM: C[M,N] = A[M,K](bf16) * Bt[N,K]^T(bf16).
// 128x128 tile, BK=32, 256 threads, 4 waves each 64x64 via 4x4 16x16x32 MFMA.
// OutT: unsigned short (bf16 store) or float (fp32 store).
// ---------------------------------------------------------------------------
template <typename OutT>
__global__ __launch_bounds__(256) void gemm_bt(const unsigned short* __restrict__ A,
                                               const unsigned short* __restrict__ Bt,
                                               OutT* __restrict__ C,
                                               int M, int N, int K)
{
    __shared__ __align__(16) unsigned short As[128 * 32];
    __shared__ __align__(16) unsigned short Bs[128 * 32];
    const int tid = threadIdx.x, lane = tid & 63, w = tid >> 6;
    const int wr = w >> 1, wc = w & 1;
    const int m0 = blockIdx.y * 128, n0 = blockIdx.x * 128;

    floatx4 acc[4][4];
#pragma unroll
    for (int i = 0; i < 4; ++i)
#pragma unroll
        for (int j = 0; j < 4; ++j) { floatx4 z = {0.f, 0.f, 0.f, 0.f}; acc[i][j] = z; }

    for (int kt = 0; kt < K; kt += 32) {
#pragma unroll
        for (int i = 0; i < 2; ++i) {
            const int is = 2 * w + i;
            const size_t aoff = (size_t)(m0 + 16 * is + (lane >> 2)) * K + kt + (lane & 3) * 8;
            const size_t boff = (size_t)(n0 + 16 * is + (lane >> 2)) * K + kt + (lane & 3) * 8;
            async_copy16(A + aoff, &As[512 * is]);
            async_copy16(Bt + boff, &Bs[512 * is]);
        }
        __syncthreads();

        bfrag af[4], bf_[4];
#pragma unroll
        for (int t = 0; t < 4; ++t)
            af[t] = *reinterpret_cast<const bfrag*>(
                &As[(64 * wr + 16 * t + (lane & 15)) * 32 + (lane >> 4) * 8]);
#pragma unroll
        for (int t = 0; t < 4; ++t)
            bf_[t] = *reinterpret_cast<const bfrag*>(
                &Bs[(64 * wc + 16 * t + (lane & 15)) * 32 + (lane >> 4) * 8]);
#pragma unroll
        for (int i = 0; i < 4; ++i)
#pragma unroll
            for (int j = 0; j < 4; ++j)
                acc[i][j] = __builtin_amdgcn_mfma_f32_16x16x32_bf16(af[i], bf_[j], acc[i][j], 0, 0, 0);
        __syncthreads();
    }

#pragma unroll
    for (int i = 0; i < 4; ++i)
#pragma unroll
        for (int j = 0; j < 4; ++j)
#pragma unroll
            for (int r = 0; r < 4; ++r) {
                const int row = m0 + 64 * wr + 16 * i + (lane >> 4) * 4 + r;
                const int col = n0 + 64 * wc + 16 * j + (lane & 15);
                float v = acc[i][j][r];
                if constexpr (sizeof(OutT) == 2)
                    C[(size_t)row * N + col] = (OutT)f2bf(v);
                else
                    C[(size_t)row * N + col] = (OutT)v;
            }
}

// ---------------------------------------------------------------------------
// Phase A: per (b,h,chunk) totals of FFT(k)*FFT(v). qkv is bf16.
// ---------------------------------------------------------------------------
__global__ __launch_bounds__(256) void hrr_phaseA(const unsigned short* __restrict__ qkv,
                                                  float* __restrict__ totals)
{
    const int blk = blockIdx.x;
    const int bh = blk / NCHUNK;
    const int chunk = blk % NCHUNK;
    const int b = bh >> 3, h = bh & 7;
    const int tid = threadIdx.x;
    const int wave = tid >> 6, lane = tid & 63;

    cpx tw[7];
    make_tw(lane, tw);

    cpx acc0 = {0.f, 0.f}, acc1 = {0.f, 0.f};
    const int s0 = chunk * CS + wave * (CS / 4);
    for (int i = 0; i < CS / 4; ++i) {
        const int s = s0 + i;
        const unsigned short* base = qkv + (size_t)(b * SS + s) * 3072 + h * 128;
        cpx k0 = { bf2f(base[1024 + lane]), 0.f };
        cpx k1 = { bf2f(base[1024 + 64 + lane]), 0.f };
        cpx v0 = { bf2f(base[2048 + lane]), 0.f };
        cpx v1 = { bf2f(base[2048 + 64 + lane]), 0.f };
        fft128_fwd(k0, k1, tw, lane);
        fft128_fwd(v0, v1, tw, lane);
        acc0 = cadd(acc0, cmul(k0, v0));
        acc1 = cadd(acc1, cmul(k1, v1));
    }

    __shared__ float red[4][256];
    red[wave][lane * 2 + 0] = acc0.re;
    red[wave][lane * 2 + 1] = acc0.im;
    red[wave][128 + lane * 2 + 0] = acc1.re;
    red[wave][128 + lane * 2 + 1] = acc1.im;
    __syncthreads();

    float s4 = red[0][tid] + red[1][tid] + red[2][tid] + red[3][tid];
    totals[((size_t)bh * NCHUNK + chunk) * 256 + tid] = s4;
}

// ---------------------------------------------------------------------------
// Phase B: exclusive scan of chunk totals
// ---------------------------------------------------------------------------
__global__ __launch_bounds__(256) void hrr_phaseB(float* __restrict__ totals)
{
    const int bh = blockIdx.x;
    const int t = threadIdx.x;
    float run = 0.f;
    for (int c = 0; c < NCHUNK; ++c) {
        const size_t idx = ((size_t)bh * NCHUNK + c) * 256 + t;
        float v = totals[idx];
        totals[idx] = run;
        run += v;
    }
}

// ---------------------------------------------------------------------------
// Phase C: in-chunk scan + unbind + inverse FFT -> vals (bf16). qkv is bf16.
// ---------------------------------------------------------------------------
__global__ __launch_bounds__(256) void hrr_phaseC(const unsigned short* __restrict__ qkv,
                                                  const float* __restrict__ totals,
                                                  unsigned short* __restrict__ vals)
{
    __shared__ float Pf[CS * 256];   // 64 KB

    const int blk = blockIdx.x;
    const int bh = blk / NCHUNK;
    const int chunk = blk % NCHUNK;
    const int b = bh >> 3, h = bh & 7;
    const int tid = threadIdx.x;
    const int wave = tid >> 6, lane = tid & 63;

    cpx tw[7];
    make_tw(lane, tw);

    for (int i = 0; i < CS / 4; ++i) {
        const int sl = wave * (CS / 4) + i;
        const int s = chunk * CS + sl;
        const unsigned short* base = qkv + (size_t)(b * SS + s) * 3072 + h * 128;
        cpx k0 = { bf2f(base[1024 + lane]), 0.f };
        cpx k1 = { bf2f(base[1024 + 64 + lane]), 0.f };
        cpx v0 = { bf2f(base[2048 + lane]), 0.f };
        cpx v1 = { bf2f(base[2048 + 64 + lane]), 0.f };
        fft128_fwd(k0, k1, tw, lane);
        fft128_fwd(v0, v1, tw, lane);
        cpx p0 = cmul(k0, v0);
        cpx p1 = cmul(k1, v1);
        float* row = &Pf[sl * 256];
        row[lane * 2 + 0] = p0.re;
        row[lane * 2 + 1] = p0.im;
        row[128 + lane * 2 + 0] = p1.re;
        row[128 + lane * 2 + 1] = p1.im;
    }
    __syncthreads();

    {
        float run = totals[((size_t)bh * NCHUNK + chunk) * 256 + tid];
#pragma unroll 8
        for (int s = 0; s < CS; ++s) {
            run += Pf[s * 256 + tid];
            Pf[s * 256 + tid] = run;
        }
    }
    __syncthreads();

    for (int i = 0; i < CS / 4; ++i) {
        const int sl = wave * (CS / 4) + i;
        const int s = chunk * CS + sl;
        const unsigned short* base = qkv + (size_t)(b * SS + s) * 3072 + h * 128;
        cpx q0 = { bf2f(base[lane]), 0.f };
        cpx q1 = { bf2f(base[64 + lane]), 0.f };
        fft128_fwd(q0, q1, tw, lane);
        const float* row = &Pf[sl * 256];
        cpx c0 = { row[lane * 2 + 0], row[lane * 2 + 1] };
        cpx c1 = { row[128 + lane * 2 + 0], row[128 + lane * 2 + 1] };
        cpx u0 = cmul_cj(c0, q0);
        cpx u1 = cmul_cj(c1, q1);
        fft128_inv(u0, u1, tw, lane);
        unsigned short* o = vals + (size_t)(b * SS + s) * DD + h * 128;
        o[lane] = f2bf(u0.re);
        o[64 + lane] = f2bf(u1.re);
    }
}

// ---------------------------------------------------------------------------
// Launch
// ---------------------------------------------------------------------------
extern "C" void kernel_launch(void* const* d_in, const int* in_sizes, int n_in,
                              void* d_out, int out_size, void* d_ws, size_t ws_size,
                              hipStream_t stream) {
    const float* x     = (const float*)d_in[0];   // [B,S,D]
    const float* w_qkv = (const float*)d_in[1];   // [D, 3D]
    const float* w_out = (const float*)d_in[2];   // [D, D]
    float* out = (float*)d_out;                   // [B,S,D]

    // Workspace layout (~178 MB total):
    //   qkv    bf16 [16384,3072]  100.7 MB
    //   xb     bf16 [16384,1024]   33.6 MB
    //   vals   bf16 [16384,1024]   33.6 MB
    //   totals fp32 [32,64,256]     2.1 MB
    //   wqkvt  bf16 [3072,1024]     6.3 MB
    //   woutt  bf16 [1024,1024]     2.1 MB
    unsigned short* qkv  = (unsigned short*)d_ws;
    unsigned short* xb   = qkv + (size_t)MROWS * 3072;
    unsigned short* vals = xb + (size_t)MROWS * DD;
    float* totals        = (float*)(vals + (size_t)MROWS * DD);
    unsigned short* wqkvt = (unsigned short*)(totals + (size_t)32 * 64 * 256);
    unsigned short* woutt = wqkvt + (size_t)3072 * 1024;

    // 0) input prep: x -> bf16; weights transpose + bf16
    convert_bf16<<<(MROWS * DD) / (256 * 8), 256, 0, stream>>>(x, xb);
    transpose_rn<<<dim3(3072 / 32, 1024 / 32), 256, 0, stream>>>(w_qkv, wqkvt, 1024, 3072);
    transpose_rn<<<dim3(1024 / 32, 1024 / 32), 256, 0, stream>>>(w_out, woutt, 1024, 1024);

    // 1) qkv = x @ w_qkv  (bf16 in, bf16 out)
    gemm_bt<unsigned short><<<dim3(3072 / 128, MROWS / 128), 256, 0, stream>>>(
        xb, wqkvt, qkv, MROWS, 3072, DD);

    // 2) chunk totals of FK*FV
    hrr_phaseA<<<BB * HH * NCHUNK, 256, 0, stream>>>(qkv, totals);

    // 3) exclusive scan of chunk totals
    hrr_phaseB<<<BB * HH, 256, 0, stream>>>(totals);

    // 4) in-chunk scan + unbind + inverse FFT -> vals (bf16)
    hrr_phaseC<<<BB * HH * NCHUNK, 256, 0, stream>>>(qkv, totals, vals);

    // 5) out = vals @ w_out  (bf16 in, fp32 out)
    gemm_bt<float><<<dim3(DD / 128, MROWS / 128), 256, 0, stream>>>(
        vals, woutt, out, MROWS, DD, DD);
}

// Round 5
// 433.617 us; speedup vs baseline: 4.5039x; 1.3059x over previous
//
#include <hip/hip_runtime.h>

// Problem constants
static constexpr int BB = 4;
static constexpr int SS = 4096;
static constexpr int DD = 1024;
static constexpr int HH = 8;
static constexpr int HD = 128;     // FFT length
static constexpr int CS = 32;      // scan chunk size (positions per block)
static constexpr int NCHUNK = SS / CS;   // 128
static constexpr int MROWS = BB * SS;    // 16384

typedef __attribute__((ext_vector_type(8))) short bfrag;    // 8 bf16 (4 VGPRs)
typedef __attribute__((ext_vector_type(4))) float floatx4;  // MFMA acc

// ---------------------------------------------------------------------------
// bf16 helpers
// ---------------------------------------------------------------------------
__device__ __forceinline__ float bf2f(unsigned int u) {   // low 16 bits = bf16
    return __uint_as_float((u & 0xFFFFu) << 16);
}
__device__ __forceinline__ unsigned short f2bf(float f) {  // RNE
    unsigned int x = __float_as_uint(f);
    unsigned int r = x + 0x7FFFu + ((x >> 16) & 1u);
    return (unsigned short)(r >> 16);
}
__device__ __forceinline__ unsigned int pack_rne(float a, float b) {
    return ((unsigned int)f2bf(a)) | (((unsigned int)f2bf(b)) << 16);
}

// async global->LDS, 16B per lane; LDS dest = wave-uniform base + lane*16
__device__ __forceinline__ void async_copy16(const void* g, void* l) {
    __builtin_amdgcn_global_load_lds(
        (const __attribute__((address_space(1))) unsigned int*)g,
        (__attribute__((address_space(3))) unsigned int*)l, 16, 0, 0);
}

// ---------------------------------------------------------------------------
// Complex helpers
// ---------------------------------------------------------------------------
struct cpx { float re, im; };

__device__ __forceinline__ cpx cadd(cpx a, cpx b) { return {a.re + b.re, a.im + b.im}; }
__device__ __forceinline__ cpx csub(cpx a, cpx b) { return {a.re - b.re, a.im - b.im}; }
__device__ __forceinline__ cpx cmul(cpx a, cpx b) {
    return { fmaf(a.re, b.re, -a.im * b.im), fmaf(a.re, b.im, a.im * b.re) };
}
__device__ __forceinline__ cpx cmul_cj(cpx a, cpx b) {   // a * conj(b)
    return { fmaf(a.re, b.re, a.im * b.im), fmaf(a.im, b.re, -a.re * b.im) };
}
__device__ __forceinline__ cpx shflx(cpx x, int m) {
    return { __shfl_xor(x.re, m), __shfl_xor(x.im, m) };
}
__device__ __forceinline__ cpx shfl_at(cpx x, int src) {
    return { __shfl(x.re, src), __shfl(x.im, src) };
}

// bin held at (reg r, lane l) is n = 2*rev6(l) + r (bit-reversed DIF output).
// Conjugate pair bin (-n mod 128) stays in the same reg. Pair lane:
//   reg1: l ^ 63;  reg0: rev6((64 - rev6(l)) & 63)
__device__ __forceinline__ int pair_lane_even(int l) {
    int m = (int)(__brev((unsigned)l) >> 26);
    int mp = (64 - m) & 63;
    return (int)(__brev((unsigned)mp) >> 26);
}

__device__ __forceinline__ void make_tw(int lane, cpx tw[7]) {
    const float NEG2PI = -6.28318530717958647692f;
    float a0 = NEG2PI * (float)lane * (1.0f / 128.0f);
    tw[0] = { __cosf(a0), __sinf(a0) };
    int d = 32;
#pragma unroll
    for (int s = 1; s <= 6; ++s) {
        int i = lane & (d - 1);
        float a = NEG2PI * (float)i / (float)(2 * d);
        tw[s] = { __cosf(a), __sinf(a) };
        d >>= 1;
    }
}

// Forward DIF FFT-128 (complex): natural in (x0=pos lane, x1=pos lane+64),
// bit-reversed-permuted out. Unnormalized.
__device__ __forceinline__ void fft128_fwd(cpx& x0, cpx& x1, const cpx tw[7], int lane) {
    cpx a = x0, b = x1;
    x0 = cadd(a, b);
    x1 = cmul(csub(a, b), tw[0]);
    int d = 32;
#pragma unroll
    for (int s = 1; s <= 6; ++s) {
        const bool up = (lane & d) != 0;
        cpx o0 = shflx(x0, d);
        cpx o1 = shflx(x1, d);
        cpx s0 = cadd(x0, o0);
        cpx s1 = cadd(x1, o1);
        cpx d0 = cmul(csub(o0, x0), tw[s]);
        cpx d1 = cmul(csub(o1, x1), tw[s]);
        x0 = up ? d0 : s0;
        x1 = up ? d1 : s1;
        d >>= 1;
    }
}

// Inverse DIT FFT-128: consumes fwd's permuted order, natural order out, /128.
__device__ __forceinline__ void fft128_inv(cpx& x0, cpx& x1, const cpx tw[7], int lane) {
    int d = 1;
#pragma unroll
    for (int s = 6; s >= 1; --s) {
        const bool up = (lane & d) != 0;
        cpx o0 = shflx(x0, d);
        cpx o1 = shflx(x1, d);
        cpx b0 = up ? x0 : o0;
        cpx a0 = up ? o0 : x0;
        cpx b1 = up ? x1 : o1;
        cpx a1 = up ? o1 : x1;
        cpx t0 = cmul_cj(b0, tw[s]);
        cpx t1 = cmul_cj(b1, tw[s]);
        x0 = up ? csub(a0, t0) : cadd(a0, t0);
        x1 = up ? csub(a1, t1) : cadd(a1, t1);
        d <<= 1;
    }
    cpx t = cmul_cj(x1, tw[0]);
    cpx a = x0;
    const float inv = 0.0078125f;
    x0 = { (a.re + t.re) * inv, (a.im + t.im) * inv };
    x1 = { (a.re - t.re) * inv, (a.im - t.im) * inv };
}

// ---------------------------------------------------------------------------
// x fp32 -> bf16 (RNE), 8 elems/thread
// ---------------------------------------------------------------------------
__global__ __launch_bounds__(256) void convert_bf16(const float* __restrict__ X,
                                                    unsigned short* __restrict__ Y)
{
    const size_t i = ((size_t)blockIdx.x * 256 + threadIdx.x) * 8;
    float4 v0 = *reinterpret_cast<const float4*>(X + i);
    float4 v1 = *reinterpret_cast<const float4*>(X + i + 4);
    uint4 p = { pack_rne(v0.x, v0.y), pack_rne(v0.z, v0.w),
                pack_rne(v1.x, v1.y), pack_rne(v1.z, v1.w) };
    *reinterpret_cast<uint4*>(Y + i) = p;
}

// Transpose + RNE bf16: W fp32 [K,N] -> T bf16 [N,K]
__global__ __launch_bounds__(256) void transpose_rn(const float* __restrict__ W,
                                                    unsigned short* __restrict__ T,
                                                    int K, int N)
{
    __shared__ float tile[32][33];
    const int n0 = blockIdx.x * 32, k0 = blockIdx.y * 32;
    const int r = threadIdx.x >> 5, c = threadIdx.x & 31;
#pragma unroll
    for (int i = 0; i < 4; ++i)
        tile[r + 8 * i][c] = W[(size_t)(k0 + r + 8 * i) * N + n0 + c];
    __syncthreads();
#pragma unroll
    for (int i = 0; i < 4; ++i) {
        float v = tile[c][r + 8 * i];
        T[(size_t)(n0 + r + 8 * i) * K + k0 + c] = f2bf(v);
    }
}

// ---------------------------------------------------------------------------
// m97-style bf16 GEMM: C[M,N] = A[M,K](bf16) * Bt[N,K]^T(bf16).
// ---------------------------------------------------------------------------
template <typename OutT>
__global__ __launch_bounds__(256) void gemm_bt(const unsigned short* __restrict__ A,
                                               const unsigned short* __restrict__ Bt,
                                               OutT* __restrict__ C,
                                               int M, int N, int K)
{
    __shared__ __align__(16) unsigned short As[128 * 32];
    __shared__ __align__(16) unsigned short Bs[128 * 32];
    const int tid = threadIdx.x, lane = tid & 63, w = tid >> 6;
    const int wr = w >> 1, wc = w & 1;
    const int m0 = blockIdx.y * 128, n0 = blockIdx.x * 128;

    floatx4 acc[4][4];
#pragma unroll
    for (int i = 0; i < 4; ++i)
#pragma unroll
        for (int j = 0; j < 4; ++j) { floatx4 z = {0.f, 0.f, 0.f, 0.f}; acc[i][j] = z; }

    for (int kt = 0; kt < K; kt += 32) {
#pragma unroll
        for (int i = 0; i < 2; ++i) {
            const int is = 2 * w + i;
            const size_t aoff = (size_t)(m0 + 16 * is + (lane >> 2)) * K + kt + (lane & 3) * 8;
            const size_t boff = (size_t)(n0 + 16 * is + (lane >> 2)) * K + kt + (lane & 3) * 8;
            async_copy16(A + aoff, &As[512 * is]);
            async_copy16(Bt + boff, &Bs[512 * is]);
        }
        __syncthreads();

        bfrag af[4], bf_[4];
#pragma unroll
        for (int t = 0; t < 4; ++t)
            af[t] = *reinterpret_cast<const bfrag*>(
                &As[(64 * wr + 16 * t + (lane & 15)) * 32 + (lane >> 4) * 8]);
#pragma unroll
        for (int t = 0; t < 4; ++t)
            bf_[t] = *reinterpret_cast<const bfrag*>(
                &Bs[(64 * wc + 16 * t + (lane & 15)) * 32 + (lane >> 4) * 8]);
#pragma unroll
        for (int i = 0; i < 4; ++i)
#pragma unroll
            for (int j = 0; j < 4; ++j)
                acc[i][j] = __builtin_amdgcn_mfma_f32_16x16x32_bf16(af[i], bf_[j], acc[i][j], 0, 0, 0);
        __syncthreads();
    }

#pragma unroll
    for (int i = 0; i < 4; ++i)
#pragma unroll
        for (int j = 0; j < 4; ++j)
#pragma unroll
            for (int r = 0; r < 4; ++r) {
                const int row = m0 + 64 * wr + 16 * i + (lane >> 4) * 4 + r;
                const int col = n0 + 64 * wc + 16 * j + (lane & 15);
                float v = acc[i][j][r];
                if constexpr (sizeof(OutT) == 2)
                    C[(size_t)row * N + col] = (OutT)f2bf(v);
                else
                    C[(size_t)row * N + col] = (OutT)v;
            }
}

// ---------------------------------------------------------------------------
// Phase A: one packed FFT Z=FFT(k+iv) per position; P = FK*FV via conjugate
// pairing: P[n] = -i*(Z[n]^2 - conj(Z[n']^2))/4, n' = -n. Stores P (bf16
// packed, permuted array-position order) and per-chunk totals (fp32).
// P layout: [bh][s][p], p=0..127 = array position (p<64: reg0 lane p).
// Component index comp = 2p + {0:re, 1:im}.
// ---------------------------------------------------------------------------
__global__ __launch_bounds__(256) void hrr_phaseA(const unsigned short* __restrict__ qkv,
                                                  unsigned int* __restrict__ P,
                                                  float* __restrict__ totals)
{
    const int blk = blockIdx.x;
    const int bh = blk / NCHUNK;
    const int chunk = blk % NCHUNK;
    const int b = bh >> 3, h = bh & 7;
    const int tid = threadIdx.x;
    const int wave = tid >> 6, lane = tid & 63;

    cpx tw[7];
    make_tw(lane, tw);
    const int pl0 = pair_lane_even(lane);
    const int pl1 = lane ^ 63;

    cpx acc0 = {0.f, 0.f}, acc1 = {0.f, 0.f};
    const int s0 = chunk * CS + wave * (CS / 4);
    for (int i = 0; i < CS / 4; ++i) {
        const int s = s0 + i;
        const unsigned short* base = qkv + (size_t)(b * SS + s) * 3072 + h * 128;
        cpx z0 = { bf2f(base[1024 + lane]),      bf2f(base[2048 + lane]) };
        cpx z1 = { bf2f(base[1024 + 64 + lane]), bf2f(base[2048 + 64 + lane]) };
        fft128_fwd(z0, z1, tw, lane);
        cpx sq0 = cmul(z0, z0);
        cpx sq1 = cmul(z1, z1);
        cpx sp0 = shfl_at(sq0, pl0);
        cpx sp1 = shfl_at(sq1, pl1);
        cpx p0 = { 0.25f * (sq0.im + sp0.im), 0.25f * (sp0.re - sq0.re) };
        cpx p1 = { 0.25f * (sq1.im + sp1.im), 0.25f * (sp1.re - sq1.re) };
        acc0 = cadd(acc0, p0);
        acc1 = cadd(acc1, p1);
        unsigned int* prow = P + ((size_t)bh * SS + s) * 128;
        prow[lane]      = pack_rne(p0.re, p0.im);
        prow[64 + lane] = pack_rne(p1.re, p1.im);
    }

    __shared__ float red[4][256];
    red[wave][lane * 2 + 0] = acc0.re;
    red[wave][lane * 2 + 1] = acc0.im;
    red[wave][128 + lane * 2 + 0] = acc1.re;
    red[wave][128 + lane * 2 + 1] = acc1.im;
    __syncthreads();

    float s4 = red[0][tid] + red[1][tid] + red[2][tid] + red[3][tid];
    totals[((size_t)bh * NCHUNK + chunk) * 256 + tid] = s4;
}

// ---------------------------------------------------------------------------
// Phase B: exclusive scan of chunk totals over 128 chunks per (bh, comp)
// ---------------------------------------------------------------------------
__global__ __launch_bounds__(256) void hrr_phaseB(float* __restrict__ totals)
{
    const int bh = blockIdx.x;
    const int t = threadIdx.x;
    float run = 0.f;
#pragma unroll 4
    for (int c = 0; c < NCHUNK; ++c) {
        const size_t idx = ((size_t)bh * NCHUNK + c) * 256 + t;
        float v = totals[idx];
        totals[idx] = run;
        run += v;
    }
}

// ---------------------------------------------------------------------------
// Phase C: load P (bf16) -> fp32 LDS, in-chunk scan, then paired unbind:
// Zq = FFT(q1 + i q2); conj(FQ1)=(conjA+B)/2, conj(FQ2)=i(conjA-B)/2 (B = Zq
// at pair lane); U = C1*conjFQ1 + i*C2*conjFQ2; IFFT(U) -> vals1=Re, vals2=Im.
// ---------------------------------------------------------------------------
__global__ __launch_bounds__(256) void hrr_phaseC(const unsigned short* __restrict__ qkv,
                                                  const unsigned int* __restrict__ P,
                                                  const float* __restrict__ totals,
                                                  unsigned short* __restrict__ vals)
{
    __shared__ float Pf[CS * 256];   // 32 KB

    const int blk = blockIdx.x;
    const int bh = blk / NCHUNK;
    const int chunk = blk % NCHUNK;
    const int b = bh >> 3, h = bh & 7;
    const int tid = threadIdx.x;
    const int wave = tid >> 6, lane = tid & 63;

    cpx tw[7];
    make_tw(lane, tw);
    const int pl0 = pair_lane_even(lane);
    const int pl1 = lane ^ 63;

    // Load P for this chunk into LDS as fp32 (comp = 2p + part)
#pragma unroll
    for (int it = 0; it < CS / 4; ++it) {
        const int sl = it * 4 + wave;
        const int s = chunk * CS + sl;
        const unsigned int* prow = P + ((size_t)bh * SS + s) * 128;
        unsigned int a = prow[lane];
        unsigned int c = prow[64 + lane];
        float2 fa = { bf2f(a), bf2f(a >> 16) };
        float2 fc = { bf2f(c), bf2f(c >> 16) };
        *reinterpret_cast<float2*>(&Pf[sl * 256 + 2 * lane]) = fa;
        *reinterpret_cast<float2*>(&Pf[sl * 256 + 128 + 2 * lane]) = fc;
    }
    __syncthreads();

    // Component-parallel inclusive scan over the chunk
    {
        float run = totals[((size_t)bh * NCHUNK + chunk) * 256 + tid];
#pragma unroll 8
        for (int s = 0; s < CS; ++s) {
            run += Pf[s * 256 + tid];
            Pf[s * 256 + tid] = run;
        }
    }
    __syncthreads();

    // Paired unbind + inverse FFT: wave handles 8 positions = 4 pairs
    for (int i = 0; i < CS / 8; ++i) {
        const int sl = wave * (CS / 4) + 2 * i;
        const int s1 = chunk * CS + sl;
        const unsigned short* b1 = qkv + (size_t)(b * SS + s1) * 3072 + h * 128;
        const unsigned short* b2 = b1 + 3072;
        cpx z0 = { bf2f(b1[lane]),      bf2f(b2[lane]) };
        cpx z1 = { bf2f(b1[64 + lane]), bf2f(b2[64 + lane]) };
        fft128_fwd(z0, z1, tw, lane);
        cpx B0 = shfl_at(z0, pl0);
        cpx B1 = shfl_at(z1, pl1);
        // conj(FQ1) = (conj A + B)/2 ; conj(FQ2) = i*(conj A - B)/2
        cpx cf1_0 = { 0.5f * (z0.re + B0.re), 0.5f * (B0.im - z0.im) };
        cpx cf1_1 = { 0.5f * (z1.re + B1.re), 0.5f * (B1.im - z1.im) };
        cpx cf2_0 = { 0.5f * (z0.im + B0.im), 0.5f * (z0.re - B0.re) };
        cpx cf2_1 = { 0.5f * (z1.im + B1.im), 0.5f * (z1.re - B1.re) };

        const float* r1 = &Pf[sl * 256];
        const float* r2 = r1 + 256;
        float2 t0 = *reinterpret_cast<const float2*>(&r1[2 * lane]);
        float2 t1 = *reinterpret_cast<const float2*>(&r1[128 + 2 * lane]);
        float2 t2 = *reinterpret_cast<const float2*>(&r2[2 * lane]);
        float2 t3 = *reinterpret_cast<const float2*>(&r2[128 + 2 * lane]);
        cpx C1_0 = { t0.x, t0.y }, C1_1 = { t1.x, t1.y };
        cpx C2_0 = { t2.x, t2.y }, C2_1 = { t3.x, t3.y };

        cpx a0 = cmul(C1_0, cf1_0), w0 = cmul(C2_0, cf2_0);
        cpx a1 = cmul(C1_1, cf1_1), w1 = cmul(C2_1, cf2_1);
        cpx u0 = { a0.re - w0.im, a0.im + w0.re };   // a + i*w
        cpx u1 = { a1.re - w1.im, a1.im + w1.re };
        fft128_inv(u0, u1, tw, lane);

        unsigned short* o1 = vals + (size_t)(b * SS + s1) * DD + h * 128;
        unsigned short* o2 = o1 + DD;
        o1[lane]      = f2bf(u0.re);
        o1[64 + lane] = f2bf(u1.re);
        o2[lane]      = f2bf(u0.im);
        o2[64 + lane] = f2bf(u1.im);
    }
}

// ---------------------------------------------------------------------------
// Launch
// ---------------------------------------------------------------------------
extern "C" void kernel_launch(void* const* d_in, const int* in_sizes, int n_in,
                              void* d_out, int out_size, void* d_ws, size_t ws_size,
                              hipStream_t stream) {
    const float* x     = (const float*)d_in[0];   // [B,S,D]
    const float* w_qkv = (const float*)d_in[1];   // [D, 3D]
    const float* w_out = (const float*)d_in[2];   // [D, D]
    float* out = (float*)d_out;                   // [B,S,D]

    // Workspace layout (~247.5 MB total):
    //   qkv    bf16 [16384,3072]       100.7 MB
    //   xb     bf16 [16384,1024]        33.6 MB
    //   vals   bf16 [16384,1024]        33.6 MB
    //   P      uint [32,4096,128]       67.1 MB  (bf16 re,im packed)
    //   totals fp32 [32,128,256]         4.2 MB
    //   wqkvt  bf16 [3072,1024]          6.3 MB
    //   woutt  bf16 [1024,1024]          2.1 MB
    unsigned short* qkv  = (unsigned short*)d_ws;
    unsigned short* xb   = qkv + (size_t)MROWS * 3072;
    unsigned short* vals = xb + (size_t)MROWS * DD;
    unsigned int* P      = (unsigned int*)(vals + (size_t)MROWS * DD);
    float* totals        = (float*)(P + (size_t)32 * SS * 128);
    unsigned short* wqkvt = (unsigned short*)(totals + (size_t)32 * NCHUNK * 256);
    unsigned short* woutt = wqkvt + (size_t)3072 * 1024;

    // 0) input prep
    convert_bf16<<<(MROWS * DD) / (256 * 8), 256, 0, stream>>>(x, xb);
    transpose_rn<<<dim3(3072 / 32, 1024 / 32), 256, 0, stream>>>(w_qkv, wqkvt, 1024, 3072);
    transpose_rn<<<dim3(1024 / 32, 1024 / 32), 256, 0, stream>>>(w_out, woutt, 1024, 1024);

    // 1) qkv = x @ w_qkv
    gemm_bt<unsigned short><<<dim3(3072 / 128, MROWS / 128), 256, 0, stream>>>(
        xb, wqkvt, qkv, MROWS, 3072, DD);

    // 2) packed FFT -> P + chunk totals
    hrr_phaseA<<<BB * HH * NCHUNK, 256, 0, stream>>>(qkv, P, totals);

    // 3) exclusive scan of chunk totals
    hrr_phaseB<<<BB * HH, 256, 0, stream>>>(totals);

    // 4) scan P in-chunk + paired unbind + IFFT -> vals
    hrr_phaseC<<<BB * HH * NCHUNK, 256, 0, stream>>>(qkv, P, totals, vals);

    // 5) out = vals @ w_out
    gemm_bt<float><<<dim3(DD / 128, MROWS / 128), 256, 0, stream>>>(
        vals, woutt, out, MROWS, DD, DD);
}